// Round 1
// baseline (413.562 us; speedup 1.0000x reference)
//
#include <hip/hip_runtime.h>
#include <math.h>

typedef float floatx4 __attribute__((ext_vector_type(4)));
typedef short short8 __attribute__((ext_vector_type(8)));

#define SIM_CAP 0.99999f   // 1 - EPS
#define MARGIN_ 0.1f
#define THRESH_ 0.5f

__device__ __forceinline__ unsigned short f2bf(float f){
  unsigned int x = __float_as_uint(f);
  x += 0x7FFFu + ((x >> 16) & 1u);   // round-to-nearest-even
  return (unsigned short)(x >> 16);
}

// ---------------- kernel 1: row L2-normalize f32 -> bf16 ----------------
// one wave per row, D=512 fixed: lane handles 8 consecutive floats
__global__ __launch_bounds__(64) void k_norm(const float* __restrict__ feats,
                                             unsigned short* __restrict__ fbf){
  const int row = blockIdx.x;
  const int l = threadIdx.x;
  const float* rp = feats + (size_t)row * 512;
  float4 v0 = ((const float4*)rp)[2 * l];
  float4 v1 = ((const float4*)rp)[2 * l + 1];
  float ss = v0.x*v0.x + v0.y*v0.y + v0.z*v0.z + v0.w*v0.w
           + v1.x*v1.x + v1.y*v1.y + v1.z*v1.z + v1.w*v1.w;
  #pragma unroll
  for(int m = 1; m < 64; m <<= 1) ss += __shfl_xor(ss, m);
  const float rn = 1.0f / sqrtf(ss);
  short8 pk;
  pk[0] = (short)f2bf(v0.x*rn); pk[1] = (short)f2bf(v0.y*rn);
  pk[2] = (short)f2bf(v0.z*rn); pk[3] = (short)f2bf(v0.w*rn);
  pk[4] = (short)f2bf(v1.x*rn); pk[5] = (short)f2bf(v1.y*rn);
  pk[6] = (short)f2bf(v1.z*rn); pk[7] = (short)f2bf(v1.w*rn);
  ((short8*)(fbf + (size_t)row * 512))[l] = pk;
}

// ---------------- pass 1: Gram tile + per-row stats ----------------
// 128x128 tile per block, 4 waves as 2x2 of 64x64, 16x16x32 bf16 MFMA, BK=32.
__global__ __launch_bounds__(256) void k_pass1(const unsigned short* __restrict__ fbf,
                                               const int* __restrict__ labels,
                                               float* __restrict__ part, // [6][ncb][Bn]
                                               int Bn, int ncb){
  __shared__ __align__(16) unsigned short Ald[128 * 32];
  __shared__ __align__(16) unsigned short Bld[128 * 32];
  __shared__ int Lrow[128], Lcol[128];
  __shared__ float Sps[2][128], Sns[2][128], Smin[2][128], Smax[2][128], Spc[2][128], Snc[2][128];

  const int t = threadIdx.x;
  const int lane = t & 63, wave = t >> 6;
  const int wm = wave >> 1, wn = wave & 1;
  const int lc = lane & 15, lk = lane >> 4;
  const int row0 = blockIdx.y * 128, col0 = blockIdx.x * 128;

  if(t < 128){
    Lrow[t] = labels[row0 + t];
    Lcol[t] = labels[col0 + t];
    Sps[0][t] = 0.f; Sps[1][t] = 0.f; Sns[0][t] = 0.f; Sns[1][t] = 0.f;
    Spc[0][t] = 0.f; Spc[1][t] = 0.f; Snc[0][t] = 0.f; Snc[1][t] = 0.f;
    Smin[0][t] = INFINITY;  Smin[1][t] = INFINITY;
    Smax[0][t] = -INFINITY; Smax[1][t] = -INFINITY;
  }

  floatx4 acc[4][4];
  #pragma unroll
  for(int i = 0; i < 4; i++)
    #pragma unroll
    for(int j = 0; j < 4; j++) acc[i][j] = (floatx4){0.f, 0.f, 0.f, 0.f};

  const int srow  = t >> 2;        // 0..63
  const int skoff = (t & 3) * 8;   // 0,8,16,24
  const unsigned short* gA = fbf + (size_t)(row0 + srow) * 512 + skoff;
  const unsigned short* gB = fbf + (size_t)(col0 + srow) * 512 + skoff;

  for(int k0 = 0; k0 < 512; k0 += 32){
    __syncthreads();
    ((short8*)Ald)[t]       = *(const short8*)(gA + k0);
    ((short8*)Ald)[256 + t] = *(const short8*)(gA + (size_t)64 * 512 + k0);
    ((short8*)Bld)[t]       = *(const short8*)(gB + k0);
    ((short8*)Bld)[256 + t] = *(const short8*)(gB + (size_t)64 * 512 + k0);
    __syncthreads();
    short8 av[4], bv[4];
    #pragma unroll
    for(int mi = 0; mi < 4; mi++) av[mi] = ((const short8*)Ald)[(wm*64 + mi*16 + lc)*4 + lk];
    #pragma unroll
    for(int ni = 0; ni < 4; ni++) bv[ni] = ((const short8*)Bld)[(wn*64 + ni*16 + lc)*4 + lk];
    #pragma unroll
    for(int mi = 0; mi < 4; mi++)
      #pragma unroll
      for(int ni = 0; ni < 4; ni++)
        acc[mi][ni] = __builtin_amdgcn_mfma_f32_16x16x32_bf16(av[mi], bv[ni], acc[mi][ni], 0, 0, 0);
  }

  // per-element stats. C layout: col = lane&15, row = 4*(lane>>4)+reg
  int labj[4], gj[4];
  #pragma unroll
  for(int ni = 0; ni < 4; ni++){
    const int cl = wn*64 + ni*16 + lc;
    labj[ni] = Lcol[cl]; gj[ni] = col0 + cl;
  }
  #pragma unroll
  for(int mi = 0; mi < 4; mi++){
    #pragma unroll
    for(int r = 0; r < 4; r++){
      const int rowl = wm*64 + mi*16 + lk*4 + r;
      const int labi = Lrow[rowl];
      const int gi = row0 + rowl;
      float ps = 0.f, ns = 0.f, pc = 0.f, nc = 0.f, mn = INFINITY, mx = -INFINITY;
      #pragma unroll
      for(int ni = 0; ni < 4; ni++){
        const float s = acc[mi][ni][r];
        if(labi == labj[ni]){
          if((gi != gj[ni]) && (s < SIM_CAP)){ pc += 1.f; ps += s; mn = fminf(mn, s); }
        } else {
          nc += 1.f; ns += s; mx = fmaxf(mx, s);
        }
      }
      #pragma unroll
      for(int m = 1; m < 16; m <<= 1){
        ps += __shfl_xor(ps, m); ns += __shfl_xor(ns, m);
        pc += __shfl_xor(pc, m); nc += __shfl_xor(nc, m);
        mn = fminf(mn, __shfl_xor(mn, m)); mx = fmaxf(mx, __shfl_xor(mx, m));
      }
      if(lc == 0){
        Sps[wn][rowl] += ps; Sns[wn][rowl] += ns;
        Spc[wn][rowl] += pc; Snc[wn][rowl] += nc;
        Smin[wn][rowl] = fminf(Smin[wn][rowl], mn);
        Smax[wn][rowl] = fmaxf(Smax[wn][rowl], mx);
      }
    }
  }
  __syncthreads();
  if(t < 128){
    const size_t stride = (size_t)ncb * Bn;
    const size_t base = (size_t)blockIdx.x * Bn + row0 + t;
    part[0*stride + base] = Spc[0][t] + Spc[1][t];
    part[1*stride + base] = Snc[0][t] + Snc[1][t];
    part[2*stride + base] = Sps[0][t] + Sps[1][t];
    part[3*stride + base] = Sns[0][t] + Sns[1][t];
    part[4*stride + base] = fminf(Smin[0][t], Smin[1][t]);
    part[5*stride + base] = fmaxf(Smax[0][t], Smax[1][t]);
  }
}

// ---------------- reduce 1: fold col-block partials into row stats ----------------
// st layout [5][Bn]: 0=minpos 1=maxneg 2=meanpos 3=meanneg 4=valid1
__global__ __launch_bounds__(256) void k_reduce1(const float* __restrict__ part,
                                                 float* __restrict__ st,
                                                 int Bn, int ncb){
  const int row = blockIdx.x * 256 + threadIdx.x;
  if(row >= Bn) return;
  const size_t stride = (size_t)ncb * Bn;
  float pc = 0, ncn = 0, ps = 0, ns = 0, mn = INFINITY, mx = -INFINITY;
  for(int cb = 0; cb < ncb; cb++){
    const size_t base = (size_t)cb * Bn + row;
    pc += part[0*stride + base]; ncn += part[1*stride + base];
    ps += part[2*stride + base]; ns  += part[3*stride + base];
    mn = fminf(mn, part[4*stride + base]); mx = fmaxf(mx, part[5*stride + base]);
  }
  st[0*Bn + row] = mn;
  st[1*Bn + row] = mx;
  st[2*Bn + row] = ps / fmaxf(pc, 1.f);
  st[3*Bn + row] = ns / fmaxf(ncn, 1.f);
  st[4*Bn + row] = (pc >= 1.f && ncn >= 1.f) ? 1.f : 0.f;
}

// ---------------- pass 2: Gram tile + hard-mined exp sums ----------------
__global__ __launch_bounds__(256) void k_pass2(const unsigned short* __restrict__ fbf,
                                               const int* __restrict__ labels,
                                               const float* __restrict__ st,
                                               float* __restrict__ part, // [4][ncb][Bn]
                                               int Bn, int ncb){
  __shared__ __align__(16) unsigned short Ald[128 * 32];
  __shared__ __align__(16) unsigned short Bld[128 * 32];
  __shared__ int Lrow[128], Lcol[128];
  __shared__ float Minp[128], Maxn[128];
  __shared__ float Spe[2][128], Sne[2][128], Spsc[2][128], Snsc[2][128];

  const int t = threadIdx.x;
  const int lane = t & 63, wave = t >> 6;
  const int wm = wave >> 1, wn = wave & 1;
  const int lc = lane & 15, lk = lane >> 4;
  const int row0 = blockIdx.y * 128, col0 = blockIdx.x * 128;

  if(t < 128){
    Lrow[t] = labels[row0 + t];
    Lcol[t] = labels[col0 + t];
    Minp[t] = st[0*Bn + row0 + t];
    Maxn[t] = st[1*Bn + row0 + t];
    Spe[0][t] = 0.f;  Spe[1][t] = 0.f;  Sne[0][t] = 0.f;  Sne[1][t] = 0.f;
    Spsc[0][t] = 0.f; Spsc[1][t] = 0.f; Snsc[0][t] = 0.f; Snsc[1][t] = 0.f;
  }

  floatx4 acc[4][4];
  #pragma unroll
  for(int i = 0; i < 4; i++)
    #pragma unroll
    for(int j = 0; j < 4; j++) acc[i][j] = (floatx4){0.f, 0.f, 0.f, 0.f};

  const int srow  = t >> 2;
  const int skoff = (t & 3) * 8;
  const unsigned short* gA = fbf + (size_t)(row0 + srow) * 512 + skoff;
  const unsigned short* gB = fbf + (size_t)(col0 + srow) * 512 + skoff;

  for(int k0 = 0; k0 < 512; k0 += 32){
    __syncthreads();
    ((short8*)Ald)[t]       = *(const short8*)(gA + k0);
    ((short8*)Ald)[256 + t] = *(const short8*)(gA + (size_t)64 * 512 + k0);
    ((short8*)Bld)[t]       = *(const short8*)(gB + k0);
    ((short8*)Bld)[256 + t] = *(const short8*)(gB + (size_t)64 * 512 + k0);
    __syncthreads();
    short8 av[4], bv[4];
    #pragma unroll
    for(int mi = 0; mi < 4; mi++) av[mi] = ((const short8*)Ald)[(wm*64 + mi*16 + lc)*4 + lk];
    #pragma unroll
    for(int ni = 0; ni < 4; ni++) bv[ni] = ((const short8*)Bld)[(wn*64 + ni*16 + lc)*4 + lk];
    #pragma unroll
    for(int mi = 0; mi < 4; mi++)
      #pragma unroll
      for(int ni = 0; ni < 4; ni++)
        acc[mi][ni] = __builtin_amdgcn_mfma_f32_16x16x32_bf16(av[mi], bv[ni], acc[mi][ni], 0, 0, 0);
  }

  int labj[4], gj[4];
  #pragma unroll
  for(int ni = 0; ni < 4; ni++){
    const int cl = wn*64 + ni*16 + lc;
    labj[ni] = Lcol[cl]; gj[ni] = col0 + cl;
  }
  #pragma unroll
  for(int mi = 0; mi < 4; mi++){
    #pragma unroll
    for(int r = 0; r < 4; r++){
      const int rowl = wm*64 + mi*16 + lk*4 + r;
      const int labi = Lrow[rowl];
      const int gi = row0 + rowl;
      const float mp = Minp[rowl];
      const float mxn = Maxn[rowl];
      float pe = 0.f, ne = 0.f, psc = 0.f, nsc = 0.f;
      #pragma unroll
      for(int ni = 0; ni < 4; ni++){
        const float s = acc[mi][ni][r];
        if(labi == labj[ni]){
          if((gi != gj[ni]) && (s < SIM_CAP) && (s - MARGIN_ < mxn)){
            pe += __expf(-2.0f * (s - THRESH_)); psc += 1.f;
          }
        } else {
          if(s + MARGIN_ > mp){
            ne += __expf(40.0f * (s - THRESH_)); nsc += 1.f;
          }
        }
      }
      #pragma unroll
      for(int m = 1; m < 16; m <<= 1){
        pe  += __shfl_xor(pe, m);  ne  += __shfl_xor(ne, m);
        psc += __shfl_xor(psc, m); nsc += __shfl_xor(nsc, m);
      }
      if(lc == 0){
        Spe[wn][rowl]  += pe;  Sne[wn][rowl]  += ne;
        Spsc[wn][rowl] += psc; Snsc[wn][rowl] += nsc;
      }
    }
  }
  __syncthreads();
  if(t < 128){
    const size_t stride = (size_t)ncb * Bn;
    const size_t base = (size_t)blockIdx.x * Bn + row0 + t;
    part[0*stride + base] = Spe[0][t]  + Spe[1][t];
    part[1*stride + base] = Sne[0][t]  + Sne[1][t];
    part[2*stride + base] = Spsc[0][t] + Spsc[1][t];
    part[3*stride + base] = Snsc[0][t] + Snsc[1][t];
  }
}

// ---------------- reduce 2: per-row loss, block partial sums ----------------
__global__ __launch_bounds__(256) void k_reduce2(const float* __restrict__ part,
                                                 const float* __restrict__ st,
                                                 float* __restrict__ blk,
                                                 int Bn, int ncb){
  const int t = threadIdx.x;
  const int row = blockIdx.x * 256 + t;
  const size_t stride = (size_t)ncb * Bn;
  float pe = 0, ne = 0, psc = 0, nsc = 0;
  for(int cb = 0; cb < ncb; cb++){
    const size_t base = (size_t)cb * Bn + row;
    pe  += part[0*stride + base]; ne  += part[1*stride + base];
    psc += part[2*stride + base]; nsc += part[3*stride + base];
  }
  const float v1 = st[4*Bn + row];
  const bool valid = (v1 > 0.5f) && (psc >= 1.f) && (nsc >= 1.f);
  float rl = valid ? (0.5f * log1pf(pe) + 0.025f * log1pf(ne)) : 0.f;
  float ap = (v1 > 0.5f) ? st[2*Bn + row] : 0.f;
  float an = (v1 > 0.5f) ? st[3*Bn + row] : 0.f;
  #pragma unroll
  for(int off = 32; off; off >>= 1){
    rl += __shfl_down(rl, off); ap += __shfl_down(ap, off); an += __shfl_down(an, off);
  }
  __shared__ float red[3][4];
  const int lane = t & 63, wave = t >> 6;
  if(lane == 0){ red[0][wave] = rl; red[1][wave] = ap; red[2][wave] = an; }
  __syncthreads();
  if(t == 0){
    blk[blockIdx.x*3 + 0] = red[0][0] + red[0][1] + red[0][2] + red[0][3];
    blk[blockIdx.x*3 + 1] = red[1][0] + red[1][1] + red[1][2] + red[1][3];
    blk[blockIdx.x*3 + 2] = red[2][0] + red[2][1] + red[2][2] + red[2][3];
  }
}

__global__ void k_final(const float* __restrict__ blk, int nblk, float inv_b,
                        float* __restrict__ out){
  if(threadIdx.x == 0 && blockIdx.x == 0){
    float l = 0, a = 0, n = 0;
    for(int i = 0; i < nblk; i++){ l += blk[i*3]; a += blk[i*3 + 1]; n += blk[i*3 + 2]; }
    out[0] = l * inv_b;
    out[1] = a * inv_b;
    out[2] = n * inv_b;
  }
}

extern "C" void kernel_launch(void* const* d_in, const int* in_sizes, int n_in,
                              void* d_out, int out_size, void* d_ws, size_t ws_size,
                              hipStream_t stream){
  const float* feats = (const float*)d_in[0];
  const int* labels = (const int*)d_in[1];
  float* out = (float*)d_out;
  const int Bn  = in_sizes[1];       // 8192
  const int ncb = Bn / 128;          // 64

  char* ws = (char*)d_ws;
  unsigned short* fbf = (unsigned short*)ws;
  size_t off = (size_t)Bn * 512 * 2;                     // 8 MB
  float* part = (float*)(ws + off); off += (size_t)6 * ncb * Bn * 4;  // 12.6 MB (reused by pass2)
  float* st   = (float*)(ws + off); off += (size_t)5 * Bn * 4;
  float* blk  = (float*)(ws + off);

  k_norm<<<Bn, 64, 0, stream>>>(feats, fbf);
  dim3 g(ncb, Bn / 128);
  k_pass1<<<g, 256, 0, stream>>>(fbf, labels, part, Bn, ncb);
  k_reduce1<<<Bn / 256, 256, 0, stream>>>(part, st, Bn, ncb);
  k_pass2<<<g, 256, 0, stream>>>(fbf, labels, st, part, Bn, ncb);
  k_reduce2<<<Bn / 256, 256, 0, stream>>>(part, st, blk, Bn, ncb);
  k_final<<<1, 64, 0, stream>>>(blk, Bn / 256, 1.0f / (float)Bn, out);
}

// Round 2
// 300.530 us; speedup vs baseline: 1.3761x; 1.3761x over previous
//
#include <hip/hip_runtime.h>
#include <math.h>

typedef float floatx4 __attribute__((ext_vector_type(4)));
typedef short short8 __attribute__((ext_vector_type(8)));

#define MARGIN_ 0.1f
#define THRESH_ 0.5f

__device__ __forceinline__ unsigned short f2bf(float f){
  unsigned int x = __float_as_uint(f);
  x += 0x7FFFu + ((x >> 16) & 1u);   // round-to-nearest-even
  return (unsigned short)(x >> 16);
}

// async global->LDS, 16B per lane. LDS dest = uniform base + lane*16 (HW).
__device__ __forceinline__ void gld16(const unsigned short* g, unsigned short* l){
  __builtin_amdgcn_global_load_lds(
      (const __attribute__((address_space(1))) unsigned int*)(g),
      (__attribute__((address_space(3))) unsigned int*)(l), 16, 0, 0);
}

// ---------------- kernel 1: row L2-normalize f32 -> bf16 ----------------
__global__ __launch_bounds__(64) void k_norm(const float* __restrict__ feats,
                                             unsigned short* __restrict__ fbf){
  const int row = blockIdx.x;
  const int l = threadIdx.x;
  const float* rp = feats + (size_t)row * 512;
  float4 v0 = ((const float4*)rp)[2 * l];
  float4 v1 = ((const float4*)rp)[2 * l + 1];
  float ss = v0.x*v0.x + v0.y*v0.y + v0.z*v0.z + v0.w*v0.w
           + v1.x*v1.x + v1.y*v1.y + v1.z*v1.z + v1.w*v1.w;
  #pragma unroll
  for(int m = 1; m < 64; m <<= 1) ss += __shfl_xor(ss, m);
  const float rn = 1.0f / sqrtf(ss);
  short8 pk;
  pk[0] = (short)f2bf(v0.x*rn); pk[1] = (short)f2bf(v0.y*rn);
  pk[2] = (short)f2bf(v0.z*rn); pk[3] = (short)f2bf(v0.w*rn);
  pk[4] = (short)f2bf(v1.x*rn); pk[5] = (short)f2bf(v1.y*rn);
  pk[6] = (short)f2bf(v1.z*rn); pk[7] = (short)f2bf(v1.w*rn);
  ((short8*)(fbf + (size_t)row * 512))[l] = pk;
}

// ---------------- label histogram (exact pos/neg counts) ----------------
__global__ __launch_bounds__(256) void k_hist(const int* __restrict__ labels, int Bn,
                                              int* __restrict__ cnt){
  __shared__ int h[512];
  for(int i = threadIdx.x; i < 512; i += 256) h[i] = 0;
  __syncthreads();
  for(int i = threadIdx.x; i < Bn; i += 256) atomicAdd(&h[labels[i]], 1);
  __syncthreads();
  for(int i = threadIdx.x; i < 512; i += 256) cnt[i] = h[i];
}

// ---------------- pass 1: Gram tile + per-row stats ----------------
// 128x128 tile, 4 waves (2x2 of 64x64), 16x16x32 bf16 MFMA, BK=32.
// LDS tile: [128 rows][4 slots of 16B]; global chunk (slot^((row>>1)&3)) stored
// at slot -> ds_read_b128 fragment reads are 2-way (free) instead of 8-way.
__global__ __launch_bounds__(256) void k_pass1(const unsigned short* __restrict__ fbf,
                                               const int* __restrict__ labels,
                                               float* __restrict__ part, // [4][ncb][Bn]
                                               int Bn, int ncb){
  __shared__ __align__(16) unsigned short Ald[128 * 32];
  __shared__ __align__(16) unsigned short Bld[128 * 32];
  __shared__ int Lrow[128], Lcol[128];
  __shared__ float Sps[2][128], Stot[2][128], Smin[2][128], Smax[2][128];

  const int t = threadIdx.x;
  const int lane = t & 63, wave = t >> 6;
  const int wm = wave >> 1, wn = wave & 1;
  const int lc = lane & 15, lk = lane >> 4;
  const int row0 = blockIdx.y * 128, col0 = blockIdx.x * 128;

  if(t < 128){
    Lrow[t] = labels[row0 + t];
    Lcol[t] = labels[col0 + t];
  }

  floatx4 acc[4][4];
  #pragma unroll
  for(int i = 0; i < 4; i++)
    #pragma unroll
    for(int j = 0; j < 4; j++) acc[i][j] = (floatx4){0.f, 0.f, 0.f, 0.f};

  // staging: instr n = wave*2+i covers LDS rows [n*16, n*16+16); lane l -> row n*16+(l>>2),
  // LDS slot l&3 receives global chunk (l&3)^((l>>3)&3)  (== (row>>1)&3 xor)
  const int rsub  = lane >> 2;
  const int slotg = (lane & 3) ^ ((lane >> 3) & 3);
  const unsigned short* gA0 = fbf + (size_t)(row0 + wave*32 + rsub) * 512 + slotg * 8;
  const unsigned short* gB0 = fbf + (size_t)(col0 + wave*32 + rsub) * 512 + slotg * 8;
  unsigned short* lA0 = Ald + wave * 1024;
  unsigned short* lB0 = Bld + wave * 1024;
  const int kswz = lk ^ ((lc >> 1) & 3);   // read-side swizzle, row-base invariant

  for(int k0 = 0; k0 < 512; k0 += 32){
    __syncthreads();
    gld16(gA0 + k0,            lA0);
    gld16(gA0 + 16*512 + k0,   lA0 + 512);
    gld16(gB0 + k0,            lB0);
    gld16(gB0 + 16*512 + k0,   lB0 + 512);
    __syncthreads();
    short8 av[4], bv[4];
    #pragma unroll
    for(int mi = 0; mi < 4; mi++) av[mi] = ((const short8*)Ald)[(wm*64 + mi*16 + lc)*4 + kswz];
    #pragma unroll
    for(int ni = 0; ni < 4; ni++) bv[ni] = ((const short8*)Bld)[(wn*64 + ni*16 + lc)*4 + kswz];
    #pragma unroll
    for(int mi = 0; mi < 4; mi++)
      #pragma unroll
      for(int ni = 0; ni < 4; ni++)
        acc[mi][ni] = __builtin_amdgcn_mfma_f32_16x16x32_bf16(av[mi], bv[ni], acc[mi][ni], 0, 0, 0);
  }

  // per-row stats: ps (pos sum), tot (sum excl self), mn (min pos), mx (max neg)
  int labj[4], gj[4];
  #pragma unroll
  for(int ni = 0; ni < 4; ni++){
    const int cl = wn*64 + ni*16 + lc;
    labj[ni] = Lcol[cl]; gj[ni] = col0 + cl;
  }
  #pragma unroll
  for(int mi = 0; mi < 4; mi++){
    #pragma unroll
    for(int r = 0; r < 4; r++){
      const int rowl = wm*64 + mi*16 + lk*4 + r;
      const int labi = Lrow[rowl];
      const int gi = row0 + rowl;
      float ps = 0.f, tot = 0.f, mn = INFINITY, mx = -INFINITY;
      #pragma unroll
      for(int ni = 0; ni < 4; ni++){
        const float s = acc[mi][ni][r];
        const bool same = (labi == labj[ni]);
        const bool self = (gi == gj[ni]);
        if(!self) tot += s;
        if(same && !self){ ps += s; mn = fminf(mn, s); }
        if(!same) mx = fmaxf(mx, s);
      }
      #pragma unroll
      for(int m = 1; m < 16; m <<= 1){
        ps += __shfl_xor(ps, m); tot += __shfl_xor(tot, m);
        mn = fminf(mn, __shfl_xor(mn, m)); mx = fmaxf(mx, __shfl_xor(mx, m));
      }
      if(lc == 0){  // single writer per (wn, rowl): write-once, no init needed
        Sps[wn][rowl] = ps; Stot[wn][rowl] = tot;
        Smin[wn][rowl] = mn; Smax[wn][rowl] = mx;
      }
    }
  }
  __syncthreads();
  if(t < 128){
    const size_t stride = (size_t)ncb * Bn;
    const size_t base = (size_t)blockIdx.x * Bn + row0 + t;
    part[0*stride + base] = Sps[0][t] + Sps[1][t];
    part[1*stride + base] = Stot[0][t] + Stot[1][t];
    part[2*stride + base] = fminf(Smin[0][t], Smin[1][t]);
    part[3*stride + base] = fmaxf(Smax[0][t], Smax[1][t]);
  }
}

// ---------------- reduce 1 ----------------
// st [5][Bn]: 0=minpos 1=maxneg 2=meanpos 3=meanneg 4=valid1
__global__ __launch_bounds__(256) void k_reduce1(const float* __restrict__ part,
                                                 const int* __restrict__ labels,
                                                 const int* __restrict__ cnt,
                                                 float* __restrict__ st,
                                                 int Bn, int ncb){
  const int row = blockIdx.x * 256 + threadIdx.x;
  if(row >= Bn) return;
  const size_t stride = (size_t)ncb * Bn;
  float ps = 0, tot = 0, mn = INFINITY, mx = -INFINITY;
  for(int cb = 0; cb < ncb; cb++){
    const size_t base = (size_t)cb * Bn + row;
    ps  += part[0*stride + base];
    tot += part[1*stride + base];
    mn = fminf(mn, part[2*stride + base]);
    mx = fmaxf(mx, part[3*stride + base]);
  }
  const int c = cnt[labels[row]];
  const float pc = (float)(c - 1);
  const float nc = (float)(Bn - c);
  st[0*Bn + row] = mn;
  st[1*Bn + row] = mx;
  st[2*Bn + row] = ps / fmaxf(pc, 1.f);
  st[3*Bn + row] = (tot - ps) / fmaxf(nc, 1.f);
  st[4*Bn + row] = (pc >= 1.f && nc >= 1.f) ? 1.f : 0.f;
}

// ---------------- pass 2: Gram tile + hard-mined exp sums ----------------
__global__ __launch_bounds__(256) void k_pass2(const unsigned short* __restrict__ fbf,
                                               const int* __restrict__ labels,
                                               const float* __restrict__ st,
                                               float* __restrict__ part, // [4][ncb][Bn]
                                               int Bn, int ncb){
  __shared__ __align__(16) unsigned short Ald[128 * 32];
  __shared__ __align__(16) unsigned short Bld[128 * 32];
  __shared__ int Lrow[128], Lcol[128];
  __shared__ float Minp[128], Maxn[128];
  __shared__ float Spe[2][128], Sne[2][128], Spf[2][128], Snf[2][128];

  const int t = threadIdx.x;
  const int lane = t & 63, wave = t >> 6;
  const int wm = wave >> 1, wn = wave & 1;
  const int lc = lane & 15, lk = lane >> 4;
  const int row0 = blockIdx.y * 128, col0 = blockIdx.x * 128;

  if(t < 128){
    Lrow[t] = labels[row0 + t];
    Lcol[t] = labels[col0 + t];
    Minp[t] = st[0*Bn + row0 + t];
    Maxn[t] = st[1*Bn + row0 + t];
  }

  floatx4 acc[4][4];
  #pragma unroll
  for(int i = 0; i < 4; i++)
    #pragma unroll
    for(int j = 0; j < 4; j++) acc[i][j] = (floatx4){0.f, 0.f, 0.f, 0.f};

  const int rsub  = lane >> 2;
  const int slotg = (lane & 3) ^ ((lane >> 3) & 3);
  const unsigned short* gA0 = fbf + (size_t)(row0 + wave*32 + rsub) * 512 + slotg * 8;
  const unsigned short* gB0 = fbf + (size_t)(col0 + wave*32 + rsub) * 512 + slotg * 8;
  unsigned short* lA0 = Ald + wave * 1024;
  unsigned short* lB0 = Bld + wave * 1024;
  const int kswz = lk ^ ((lc >> 1) & 3);

  for(int k0 = 0; k0 < 512; k0 += 32){
    __syncthreads();
    gld16(gA0 + k0,            lA0);
    gld16(gA0 + 16*512 + k0,   lA0 + 512);
    gld16(gB0 + k0,            lB0);
    gld16(gB0 + 16*512 + k0,   lB0 + 512);
    __syncthreads();
    short8 av[4], bv[4];
    #pragma unroll
    for(int mi = 0; mi < 4; mi++) av[mi] = ((const short8*)Ald)[(wm*64 + mi*16 + lc)*4 + kswz];
    #pragma unroll
    for(int ni = 0; ni < 4; ni++) bv[ni] = ((const short8*)Bld)[(wn*64 + ni*16 + lc)*4 + kswz];
    #pragma unroll
    for(int mi = 0; mi < 4; mi++)
      #pragma unroll
      for(int ni = 0; ni < 4; ni++)
        acc[mi][ni] = __builtin_amdgcn_mfma_f32_16x16x32_bf16(av[mi], bv[ni], acc[mi][ni], 0, 0, 0);
  }

  int labj[4], gj[4];
  #pragma unroll
  for(int ni = 0; ni < 4; ni++){
    const int cl = wn*64 + ni*16 + lc;
    labj[ni] = Lcol[cl]; gj[ni] = col0 + cl;
  }
  #pragma unroll
  for(int mi = 0; mi < 4; mi++){
    #pragma unroll
    for(int r = 0; r < 4; r++){
      const int rowl = wm*64 + mi*16 + lk*4 + r;
      const int labi = Lrow[rowl];
      const int gi = row0 + rowl;
      const float mp  = Minp[rowl];
      const float mxn = Maxn[rowl];
      float pe = 0.f, ne = 0.f;
      bool pAny = false, nAny = false;
      #pragma unroll
      for(int ni = 0; ni < 4; ni++){
        const float s = acc[mi][ni][r];
        const bool same = (labi == labj[ni]);
        const bool self = (gi == gj[ni]);
        if(same && !self && (s - MARGIN_ < mxn)){
          pe += __expf(-2.0f * (s - THRESH_)); pAny = true;
        }
        if(!same && (s + MARGIN_ > mp)){
          ne += __expf(40.0f * (s - THRESH_)); nAny = true;
        }
      }
      // validity per row via ballot: row(lk)'s 16 lanes occupy bits [lk*16, lk*16+16)
      const unsigned long long bp = __ballot((int)pAny);
      const unsigned long long bn2 = __ballot((int)nAny);
      #pragma unroll
      for(int m = 1; m < 16; m <<= 1){
        pe += __shfl_xor(pe, m); ne += __shfl_xor(ne, m);
      }
      if(lc == 0){
        Spe[wn][rowl] = pe; Sne[wn][rowl] = ne;
        Spf[wn][rowl] = ((bp  >> (lk*16)) & 0xFFFFull) ? 1.f : 0.f;
        Snf[wn][rowl] = ((bn2 >> (lk*16)) & 0xFFFFull) ? 1.f : 0.f;
      }
    }
  }
  __syncthreads();
  if(t < 128){
    const size_t stride = (size_t)ncb * Bn;
    const size_t base = (size_t)blockIdx.x * Bn + row0 + t;
    part[0*stride + base] = Spe[0][t] + Spe[1][t];
    part[1*stride + base] = Sne[0][t] + Sne[1][t];
    part[2*stride + base] = fmaxf(Spf[0][t], Spf[1][t]);
    part[3*stride + base] = fmaxf(Snf[0][t], Snf[1][t]);
  }
}

// ---------------- reduce 2: per-row loss, block partial sums ----------------
__global__ __launch_bounds__(256) void k_reduce2(const float* __restrict__ part,
                                                 const float* __restrict__ st,
                                                 float* __restrict__ blk,
                                                 int Bn, int ncb){
  const int t = threadIdx.x;
  const int row = blockIdx.x * 256 + t;
  const size_t stride = (size_t)ncb * Bn;
  float pe = 0, ne = 0, pf = 0, nf = 0;
  for(int cb = 0; cb < ncb; cb++){
    const size_t base = (size_t)cb * Bn + row;
    pe += part[0*stride + base]; ne += part[1*stride + base];
    pf = fmaxf(pf, part[2*stride + base]); nf = fmaxf(nf, part[3*stride + base]);
  }
  const float v1 = st[4*Bn + row];
  const bool valid = (v1 > 0.5f) && (pf > 0.5f) && (nf > 0.5f);
  float rl = valid ? (0.5f * log1pf(pe) + 0.025f * log1pf(ne)) : 0.f;
  float ap = (v1 > 0.5f) ? st[2*Bn + row] : 0.f;
  float an = (v1 > 0.5f) ? st[3*Bn + row] : 0.f;
  #pragma unroll
  for(int off = 32; off; off >>= 1){
    rl += __shfl_down(rl, off); ap += __shfl_down(ap, off); an += __shfl_down(an, off);
  }
  __shared__ float red[3][4];
  const int lane = t & 63, wave = t >> 6;
  if(lane == 0){ red[0][wave] = rl; red[1][wave] = ap; red[2][wave] = an; }
  __syncthreads();
  if(t == 0){
    blk[blockIdx.x*3 + 0] = red[0][0] + red[0][1] + red[0][2] + red[0][3];
    blk[blockIdx.x*3 + 1] = red[1][0] + red[1][1] + red[1][2] + red[1][3];
    blk[blockIdx.x*3 + 2] = red[2][0] + red[2][1] + red[2][2] + red[2][3];
  }
}

__global__ void k_final(const float* __restrict__ blk, int nblk, float inv_b,
                        float* __restrict__ out){
  if(threadIdx.x == 0 && blockIdx.x == 0){
    float l = 0, a = 0, n = 0;
    for(int i = 0; i < nblk; i++){ l += blk[i*3]; a += blk[i*3 + 1]; n += blk[i*3 + 2]; }
    out[0] = l * inv_b;
    out[1] = a * inv_b;
    out[2] = n * inv_b;
  }
}

extern "C" void kernel_launch(void* const* d_in, const int* in_sizes, int n_in,
                              void* d_out, int out_size, void* d_ws, size_t ws_size,
                              hipStream_t stream){
  const float* feats = (const float*)d_in[0];
  const int* labels = (const int*)d_in[1];
  float* out = (float*)d_out;
  const int Bn  = in_sizes[1];       // 8192
  const int ncb = Bn / 128;          // 64

  char* ws = (char*)d_ws;
  unsigned short* fbf = (unsigned short*)ws;
  size_t off = (size_t)Bn * 512 * 2;                               // 8 MB
  float* part = (float*)(ws + off); off += (size_t)4 * ncb * Bn * 4; // 8.4 MB (reused by pass2)
  float* st   = (float*)(ws + off); off += (size_t)5 * Bn * 4;
  int*   cnt  = (int*)(ws + off);   off += 512 * 4;
  float* blk  = (float*)(ws + off);

  k_norm<<<Bn, 64, 0, stream>>>(feats, fbf);
  k_hist<<<1, 256, 0, stream>>>(labels, Bn, cnt);
  dim3 g(ncb, Bn / 128);
  k_pass1<<<g, 256, 0, stream>>>(fbf, labels, part, Bn, ncb);
  k_reduce1<<<Bn / 256, 256, 0, stream>>>(part, labels, cnt, st, Bn, ncb);
  k_pass2<<<g, 256, 0, stream>>>(fbf, labels, st, part, Bn, ncb);
  k_reduce2<<<Bn / 256, 256, 0, stream>>>(part, st, blk, Bn, ncb);
  k_final<<<1, 64, 0, stream>>>(blk, Bn / 256, 1.0f / (float)Bn, out);
}